// Round 5
// baseline (639.064 us; speedup 1.0000x reference)
//
// Round 9: ONE barrier per K-tile. R5=R7=R8 (~125us) proved time is invariant
// to LDS conflicts, B-read count, and vmcnt depth -> the cost is the phase
// skeleton: 4 barriers + 2 lgkm per K-tile, 8 waves lockstep, 1 block/CU.
// New iteration: stage(kt+3) | 12 ds_read(slot kt) | lgkmcnt(0) | 32 MFMA |
// vmcnt(8) | barrier. WAR safe: lgkm(0) precedes the end-of-it barrier, so
// passing it means all waves' reads COMPLETED. RAW: vmcnt(8) lands tile kt+1
// (in-flight {kt+1,kt+2,kt+3}) before the barrier. Tail: vmcnt(4)@NK-3,
// vmcnt(0)@NK-2. Swizzle + setprio + 4-slot ring kept.
#include <hip/hip_runtime.h>
#include <hip/hip_bf16.h>
#include <math.h>

#define NB 16384      // B
#define DIM 1024      // D
#define CAP 6656      // compacted capacity (count ~5461)
#define MT 52         // CAP/128 m-tiles (wo_z)
#define MT2 26        // CAP/256 m-tiles (gemm256)

using bf16 = __hip_bfloat16;
typedef __attribute__((ext_vector_type(8))) short short8;
typedef __attribute__((ext_vector_type(4))) short short4v;
typedef __attribute__((ext_vector_type(4))) float float4v;

__device__ __forceinline__ void gl_lds16(const void* g, void* l) {
  __builtin_amdgcn_global_load_lds(
      (const __attribute__((address_space(1))) unsigned int*)g,
      (__attribute__((address_space(3))) unsigned int*)l, 16, 0, 0);
}

__device__ __forceinline__ short f2bf(float x) {
  __hip_bfloat16 h = __float2bfloat16(x);
  return *reinterpret_cast<short*>(&h);
}

// bid -> (m0, n0) in 128-tiles: xcd = bid&7 owns n-panels n%8==xcd. nN%8==0.
__device__ __forceinline__ void swz(int bid, int nN, int& m0, int& n0) {
  int x = bid & 7;
  int r = bid >> 3;
  int nl = nN >> 3;
  int nLoc = r % nl;
  int m = r / nl;
  n0 = (x + 8 * nLoc) * 128;
  m0 = m * 128;
}

// 256-tile variant
__device__ __forceinline__ void swz256(int bid, int nN, int& m0, int& n0) {
  int x = bid & 7;
  int r = bid >> 3;
  int nl = nN >> 3;
  n0 = (x + 8 * (r % nl)) * 256;
  m0 = (r / nl) * 256;
}

// ---- stage one 256x32 bf16 unit into LDS -----------------------------------
// LDS layout (16KB unit, 256 rows x 32 cols bf16, 64B rows): element (row,col)
// lives at byte row*64 + ((col*2) ^ ((row&6)<<3)). Writer must stay linear
// (gl_lds: wave-uniform dest + lane*16B), so the swizzle is realized by
// permuting the per-lane GLOBAL source 16B chunk; reader applies the same XOR.
__device__ __forceinline__ void stage_unit(const bf16* __restrict__ gbase,
                                           int ld, int kc, bf16* ubase, int t) {
#pragma unroll
  for (int j = 0; j < 2; ++j) {
    int ch = t + j * 512;               // 16B chunk index, 1024 per unit
    int rg = ch >> 6;                   // 16-row group (0..15)
    int rl = (ch >> 2) & 15;            // row within group
    int cs = ((ch & 3) * 8) ^ ((rl & 6) << 2);  // swizzled col (elements)
    const bf16* src = gbase + (size_t)(rg * 16 + rl) * ld + kc + cs;
    gl_lds16(src, (void*)(ubase + ((t >> 6) << 9) + j * 4096));
  }
}

// ---------------- 256x256-tile single-barrier GEMM ----------------
// MODE 0: qkv+gate, merged img/txt halves. A(CAP,1024)@[Wqkv|WgHalf]^T N=4096.
// MODE 1: ffn1 gelu. A=zb(CAP,1024) @ Wf1T, N=4096.
// MODE 2: ffn2 split-K=2 fp32 partials. A=hb(CAP,4096) @ Wf2T, N=1024.
template <int MODE>
__global__ __launch_bounds__(512, 2) void gemm256(
    const bf16* __restrict__ A0, const bf16* __restrict__ A1,
    const bf16* __restrict__ B0, const bf16* __restrict__ Bg0,
    const bf16* __restrict__ Bg1, const float* __restrict__ bias0,
    const float* __restrict__ bias1, bf16* __restrict__ O0,
    bf16* __restrict__ O1, float* __restrict__ P,
    const int* __restrict__ cntp) {
  const int cnt = *cntp;
  int bid = blockIdx.x;
  int g = 0, sk = 0, m0, n0;
  if constexpr (MODE == 0) {
    g = bid >= 416;
    bid -= g * 416;
    swz256(bid, 16, m0, n0);
  } else if constexpr (MODE == 1) {
    swz256(bid, 16, m0, n0);
  } else {
    sk = bid / 104;
    int rm = bid % 104;
    m0 = (rm >> 2) * 256;
    n0 = (rm & 3) * 256;
  }
  if (m0 >= ((cnt + 255) & ~255)) return;

  constexpr int LDA = (MODE == 2) ? 4096 : 1024;
  constexpr int LDB = (MODE == 2) ? 4096 : 1024;
  constexpr int NK = (MODE == 2) ? 64 : 32;   // BK=32 K-tiles
  const int kb = (MODE == 2) ? sk * 2048 : 0;

  const bf16* Ab;
  const bf16* Bt;
  if constexpr (MODE == 0) {
    Ab = (g ? A1 : A0) + (size_t)m0 * LDA;
    Bt = (n0 < 3072) ? B0 + (size_t)n0 * 1024
                     : (g ? Bg1 : Bg0) + (size_t)(n0 - 3072) * 1024;
  } else {
    Ab = A0 + (size_t)m0 * LDA;
    Bt = B0 + (size_t)n0 * LDB;
  }

  alignas(16) __shared__ bf16 lds[4][2][8192];  // 4-slot ring x {A,B} x 16KB
  const int t = threadIdx.x;
  const int wave = t >> 6, lane = t & 63;
  const int wm = wave >> 2, wn = wave & 3;   // 2M x 4N waves, 128x64 out/wave
  const int r16 = lane & 15, quad = lane >> 4;
  const int xorv = (quad * 8) ^ ((r16 & 6) << 2);  // swizzled k-chunk (shorts)

  // prologue: stage tiles 0..2; tile0 gated here, tiles 1,2 by loop gates
#pragma unroll
  for (int s = 0; s < 3; ++s) {
    stage_unit(Ab, LDA, kb + s * 32, &lds[s][0][0], t);
    stage_unit(Bt, LDB, kb + s * 32, &lds[s][1][0], t);
  }
  asm volatile("s_waitcnt vmcnt(8)" ::: "memory");
  __builtin_amdgcn_s_barrier();

  float4v acc[8][4] = {};
#pragma unroll 4
  for (int kt = 0; kt < NK; ++kt) {
    const int slot = kt & 3;
    // stage tile kt+3 into slot (kt+3)&3 == (kt-1)&3: its readers finished
    // (their lgkmcnt(0) precedes the end-of-(kt-1) barrier).
    if (kt + 3 < NK) {
      const int sl = (kt + 3) & 3;
      stage_unit(Ab, LDA, kb + (kt + 3) * 32, &lds[sl][0][0], t);
      stage_unit(Bt, LDB, kb + (kt + 3) * 32, &lds[sl][1][0], t);
    }
    const bf16* aU = &lds[slot][0][0];
    const bf16* bU = &lds[slot][1][0];
    short8 av[8], bv[4];
#pragma unroll
    for (int mi = 0; mi < 8; ++mi)
      av[mi] = *(const short8*)(aU + (wm * 128 + mi * 16 + r16) * 32 + xorv);
#pragma unroll
    for (int ni = 0; ni < 4; ++ni)
      bv[ni] = *(const short8*)(bU + (wn * 64 + ni * 16 + r16) * 32 + xorv);
    asm volatile("s_waitcnt lgkmcnt(0)" ::: "memory");
    __builtin_amdgcn_s_setprio(1);
#pragma unroll
    for (int mi = 0; mi < 8; ++mi)
#pragma unroll
      for (int ni = 0; ni < 4; ++ni)
        acc[mi][ni] = __builtin_amdgcn_mfma_f32_16x16x32_bf16(
            av[mi], bv[ni], acc[mi][ni], 0, 0, 0);
    __builtin_amdgcn_s_setprio(0);
    // gate: tile kt+1 landed (in-flight <= {kt+1,kt+2,kt+3}); tail shrinks.
    if (kt < NK - 3) {
      asm volatile("s_waitcnt vmcnt(8)" ::: "memory");
    } else if (kt == NK - 3) {
      asm volatile("s_waitcnt vmcnt(4)" ::: "memory");
    } else if (kt == NK - 2) {
      asm volatile("s_waitcnt vmcnt(0)" ::: "memory");
    }
    __builtin_amdgcn_s_barrier();
  }

  const int colb = n0 + wn * 64 + r16;
  if constexpr (MODE == 2) {
    float* out = P + (size_t)sk * CAP * 1024;
#pragma unroll
    for (int nf = 0; nf < 4; ++nf) {
      int gcol = colb + nf * 16;
#pragma unroll
      for (int mf = 0; mf < 8; ++mf)
#pragma unroll
        for (int r = 0; r < 4; ++r) {
          int grow = m0 + wm * 128 + mf * 16 + quad * 4 + r;
          out[(size_t)grow * 1024 + gcol] = acc[mf][nf][r];
        }
    }
  } else {
    const float* bias = (MODE == 0) ? (g ? bias1 : bias0) : bias0;
    bf16* O = (MODE == 0) ? (g ? O1 : O0) : O0;
    float bvv[4];
#pragma unroll
    for (int nf = 0; nf < 4; ++nf) bvv[nf] = bias[colb + nf * 16];
#pragma unroll
    for (int nf = 0; nf < 4; ++nf) {
      int gcol = colb + nf * 16;
#pragma unroll
      for (int mf = 0; mf < 8; ++mf)
#pragma unroll
        for (int r = 0; r < 4; ++r) {
          int grow = m0 + wm * 128 + mf * 16 + quad * 4 + r;
          float v = acc[mf][nf][r] + bvv[nf];
          if constexpr (MODE == 1)
            v = 0.5f * v * (1.f + erff(v * 0.70710678118654752f));
          O[(size_t)grow * 4096 + gcol] = __float2bfloat16(v);
        }
    }
  }
}

// ---------------- transpose + cast weight (K,N) fp32 -> (N,K) bf16 ----------
__global__ __launch_bounds__(256) void transpose_cast(
    const float* __restrict__ in, bf16* __restrict__ out, int K, int N) {
  __shared__ float tile[32][33];
  int n0 = blockIdx.x * 32, k0 = blockIdx.y * 32;
  int tx = threadIdx.x, ty = threadIdx.y;  // 32 x 8
#pragma unroll
  for (int i = 0; i < 32; i += 8)
    tile[ty + i][tx] = in[(size_t)(k0 + ty + i) * N + n0 + tx];
  __syncthreads();
#pragma unroll
  for (int i = 0; i < 32; i += 8)
    out[(size_t)(n0 + ty + i) * K + k0 + tx] = __float2bfloat16(tile[tx][ty + i]);
}

// ---------------- bias concat buffers for qkvg GEMMs ----------------
__global__ __launch_bounds__(256) void fill_bias(const float* __restrict__ bqkv,
                                                 const float* __restrict__ bg,
                                                 float* __restrict__ biasA,
                                                 float* __restrict__ biasB) {
  int i = blockIdx.x * 256 + threadIdx.x;  // < 4096
  float qv = (i < 3072) ? bqkv[i] : 0.f;
  biasA[i] = qv;
  biasB[i] = (i < 3072) ? qv : bg[i - 3072];
}

// ---------------- compaction ----------------
__global__ void zero_cnt(int* cnt) { if (threadIdx.x == 0) *cnt = 0; }

__global__ __launch_bounds__(256) void index_build(const int* __restrict__ route,
                                                   int* __restrict__ cnt,
                                                   int* __restrict__ idx,
                                                   int* __restrict__ pos) {
  int r = blockIdx.x * 256 + threadIdx.x;
  if (r < NB && route[r] == 2) {
    int p = atomicAdd(cnt, 1);
    idx[p] = r;
    pos[r] = p;
  }
}

__global__ __launch_bounds__(256) void gather_cast(
    const float* __restrict__ img, const float* __restrict__ txt,
    const int* __restrict__ cnt, const int* __restrict__ idx,
    bf16* __restrict__ xg, bf16* __restrict__ tg) {
  int n = blockIdx.x;
  if (n >= *cnt) return;
  int r = idx[n];
  int c = threadIdx.x * 4;
  float4 vi = *(const float4*)(img + (size_t)r * DIM + c);
  float4 vt = *(const float4*)(txt + (size_t)r * DIM + c);
  short4v pi, pt;
  pi[0] = f2bf(vi.x); pi[1] = f2bf(vi.y); pi[2] = f2bf(vi.z); pi[3] = f2bf(vi.w);
  pt[0] = f2bf(vt.x); pt[1] = f2bf(vt.y); pt[2] = f2bf(vt.z); pt[3] = f2bf(vt.w);
  *(short4v*)(xg + (size_t)n * DIM + c) = pi;
  *(short4v*)(tg + (size_t)n * DIM + c) = pt;
}

// ---------------- seq-len-2 attention ----------------
__global__ __launch_bounds__(256) void attn_kernel(const bf16* __restrict__ qx,
                                                   const bf16* __restrict__ tx,
                                                   bf16* __restrict__ cmean,
                                                   const int* __restrict__ cntp) {
  const int cnt = *cntp;
  int gw = blockIdx.x * 4 + (threadIdx.x >> 6);
  int lane = threadIdx.x & 63;
  int n = gw >> 4, h = gw & 15;
  if (n >= ((cnt + 127) & ~127)) return;
  const bf16* b0 = qx + (size_t)n * 4096 + h * 64 + lane;
  const bf16* b1 = tx + (size_t)n * 4096 + h * 64 + lane;
  float q0 = __bfloat162float(b0[0]);
  float k0 = __bfloat162float(b0[1024]);
  float v0 = __bfloat162float(b0[2048]);
  float q1 = __bfloat162float(b1[0]);
  float k1 = __bfloat162float(b1[1024]);
  float v1 = __bfloat162float(b1[2048]);
  float s00 = q0 * k0, s01 = q0 * k1, s10 = q1 * k0, s11 = q1 * k1;
#pragma unroll
  for (int d = 32; d > 0; d >>= 1) {
    s00 += __shfl_xor(s00, d);
    s01 += __shfl_xor(s01, d);
    s10 += __shfl_xor(s10, d);
    s11 += __shfl_xor(s11, d);
  }
  const float sc = 0.125f;
  s00 *= sc; s01 *= sc; s10 *= sc; s11 *= sc;
  float m0 = fmaxf(s00, s01), m1 = fmaxf(s10, s11);
  float e00 = expf(s00 - m0), e01 = expf(s01 - m0);
  float e10 = expf(s10 - m1), e11 = expf(s11 - m1);
  float i0 = 1.f / (e00 + e01), i1 = 1.f / (e10 + e11);
  float c0 = (e00 * i0) * v0 + (e01 * i0) * v1;
  float c1 = (e10 * i1) * v0 + (e11 * i1) * v1;
  cmean[(size_t)n * DIM + h * 64 + lane] = __float2bfloat16(0.5f * (c0 + c1));
}

// ---------------- wo_z: z = fmix + cmean@Wo + bo (128^2 structure) ---------
__global__ __launch_bounds__(256) void wo_z_kernel(
    const float* __restrict__ img, const float* __restrict__ txt,
    const bf16* __restrict__ qx, const bf16* __restrict__ tx,
    const bf16* __restrict__ WoT, const float* __restrict__ bg,
    const float* __restrict__ bo, const bf16* __restrict__ cmean,
    bf16* __restrict__ z, const int* __restrict__ cntp, const int* __restrict__ idx) {
  const int cnt = *cntp;
  int m0, n0;
  swz(blockIdx.x, 8, m0, n0);
  if (m0 >= ((cnt + 127) & ~127)) return;
  alignas(16) __shared__ bf16 sA[128 * 32];
  alignas(16) __shared__ bf16 sB[128 * 32];
  const int t = threadIdx.x;
  const int wave = t >> 6, lane = t & 63;
  const int wm = (wave >> 1) * 64, wn = (wave & 1) * 64;
  const int r16 = lane & 15, quad = lane >> 4;

  float4v acc[4][4] = {};
  for (int k0 = 0; k0 < 1024; k0 += 32) {
    if (k0) __syncthreads();
#pragma unroll
    for (int j = 0; j < 2; ++j) {
      int c = t + j * 256;
      int row = c >> 2;
      int kk = k0 + (c & 3) * 8;
      gl_lds16(WoT + (size_t)(n0 + row) * 1024 + kk, (void*)(sB + j * 2048 + wave * 512));
      gl_lds16(cmean + (size_t)(m0 + row) * 1024 + kk, (void*)(sA + j * 2048 + wave * 512));
    }
    __syncthreads();
    short8 af[4], bfr[4];
#pragma unroll
    for (int i = 0; i < 4; ++i) {
      af[i] = *(const short8*)(sA + (wm + i * 16 + r16) * 32 + quad * 8);
      bfr[i] = *(const short8*)(sB + (wn + i * 16 + r16) * 32 + quad * 8);
    }
#pragma unroll
    for (int i = 0; i < 4; ++i)
#pragma unroll
      for (int j = 0; j < 4; ++j)
        acc[i][j] =
            __builtin_amdgcn_mfma_f32_16x16x32_bf16(af[i], bfr[j], acc[i][j], 0, 0, 0);
  }
#pragma unroll
  for (int i = 0; i < 4; ++i)
#pragma unroll
    for (int j = 0; j < 4; ++j) {
      int gcol = n0 + wn + j * 16 + r16;
      float bgv = bg[gcol], bov = bo[gcol];
#pragma unroll
      for (int r = 0; r < 4; ++r) {
        int grow = m0 + wm + i * 16 + quad * 4 + r;
        float zv = 0.f;
        if (grow < cnt) {
          int orow = idx[grow];
          float gp = __bfloat162float(qx[(size_t)grow * 4096 + 3072 + gcol]) +
                     __bfloat162float(tx[(size_t)grow * 4096 + 3072 + gcol]) + bgv;
          float g = 1.f / (1.f + expf(-gp));
          size_t ii = (size_t)orow * DIM + gcol;
          float fm = g * img[ii] + (1.f - g) * txt[ii];
          zv = fm + acc[i][j][r] + bov;
        }
        z[(size_t)grow * DIM + gcol] = __float2bfloat16(zv);
      }
    }
}

// ---------------- layernorm in-place ----------------
__global__ __launch_bounds__(256) void ln_kernel(bf16* __restrict__ z,
                                                 const float* __restrict__ g,
                                                 const float* __restrict__ be,
                                                 const int* __restrict__ cntp) {
  const int cnt = *cntp;
  int b = blockIdx.x, t = threadIdx.x;
  if (b >= ((cnt + 127) & ~127)) return;
  bf16* zr = z + (size_t)b * DIM;
  float v[4];
  float s = 0.f, s2 = 0.f;
#pragma unroll
  for (int i = 0; i < 4; ++i) {
    float x = __bfloat162float(zr[t + 256 * i]);
    v[i] = x; s += x; s2 += x * x;
  }
#pragma unroll
  for (int d = 32; d > 0; d >>= 1) {
    s += __shfl_xor(s, d);
    s2 += __shfl_xor(s2, d);
  }
  __shared__ float rs[4], rs2[4];
  int w = t >> 6, lane = t & 63;
  if (!lane) { rs[w] = s; rs2[w] = s2; }
  __syncthreads();
  s = rs[0] + rs[1] + rs[2] + rs[3];
  s2 = rs2[0] + rs2[1] + rs2[2] + rs2[3];
  float mu = s * (1.f / 1024.f);
  float var = s2 * (1.f / 1024.f) - mu * mu;
  float r = rsqrtf(var + 1e-5f);
#pragma unroll
  for (int i = 0; i < 4; ++i) {
    int c = t + 256 * i;
    zr[c] = __float2bfloat16((v[i] - mu) * r * g[c] + be[c]);
  }
}

// ---------------- unified output: copy rc 0/1, reduce partials rc 2 --------
__global__ __launch_bounds__(256) void route_out(
    const float* __restrict__ img, const float* __restrict__ txt,
    const int* __restrict__ route, const int* __restrict__ pos,
    const float* __restrict__ parts, const float* __restrict__ bf2,
    float* __restrict__ out) {
  int row = blockIdx.x;
  int rc = route[row];
  int c = threadIdx.x * 4;
  float4 v;
  if (rc == 2) {
    int n = pos[row];
    float4 p0 = *(const float4*)(parts + (size_t)n * 1024 + c);
    float4 p1 = *(const float4*)(parts + (size_t)CAP * 1024 + (size_t)n * 1024 + c);
    float4 b = *(const float4*)(bf2 + c);
    v.x = p0.x + p1.x + b.x;
    v.y = p0.y + p1.y + b.y;
    v.z = p0.z + p1.z + b.z;
    v.w = p0.w + p1.w + b.w;
  } else {
    const float* src = (rc == 0) ? img : txt;
    v = *(const float4*)(src + (size_t)row * DIM + c);
  }
  *(float4*)(out + (size_t)row * DIM + c) = v;
}

extern "C" void kernel_launch(void* const* d_in, const int* in_sizes, int n_in,
                              void* d_out, int out_size, void* d_ws, size_t ws_size,
                              hipStream_t stream) {
  const float* img = (const float*)d_in[0];
  const float* txt = (const float*)d_in[1];
  const int* route = (const int*)d_in[2];
  const float* Wg = (const float*)d_in[3];
  const float* bg = (const float*)d_in[4];
  const float* Wqkv = (const float*)d_in[5];
  const float* bqkv = (const float*)d_in[6];
  const float* Wo = (const float*)d_in[7];
  const float* bo = (const float*)d_in[8];
  const float* gamma = (const float*)d_in[9];
  const float* beta = (const float*)d_in[10];
  const float* Wf1 = (const float*)d_in[11];
  const float* bf1 = (const float*)d_in[12];
  const float* Wf2 = (const float*)d_in[13];
  const float* bf2 = (const float*)d_in[14];

  char* ws = (char*)d_ws;
  size_t off = 0;
  auto alloc = [&](size_t bytes) {
    char* p = ws + off;
    off += (bytes + 255) & ~(size_t)255;
    return p;
  };
  int* cntp = (int*)alloc(256);
  int* idx = (int*)alloc((size_t)NB * 4);
  int* pos = (int*)alloc((size_t)NB * 4);
  float* biasA = (float*)alloc(4096 * 4);
  float* biasB = (float*)alloc(4096 * 4);
  bf16* WqkvT = (bf16*)alloc((size_t)3072 * 1024 * 2);
  bf16* WgTopT = (bf16*)alloc((size_t)1024 * 1024 * 2);
  bf16* WgBotT = (bf16*)alloc((size_t)1024 * 1024 * 2);
  bf16* WoT = (bf16*)alloc((size_t)1024 * 1024 * 2);
  bf16* Wf1T = (bf16*)alloc((size_t)4096 * 1024 * 2);
  bf16* Wf2T = (bf16*)alloc((size_t)1024 * 4096 * 2);
  bf16* xg = (bf16*)alloc((size_t)CAP * 1024 * 2);
  bf16* tg = (bf16*)alloc((size_t)CAP * 1024 * 2);
  bf16* qx = (bf16*)alloc((size_t)CAP * 4096 * 2);  // qkv+gate (img); later h
  bf16* tx = (bf16*)alloc((size_t)CAP * 4096 * 2);  // qkv+gate (txt); later partials
  bf16* cmean = (bf16*)alloc((size_t)CAP * 1024 * 2);
  bf16* zb = (bf16*)alloc((size_t)CAP * 1024 * 2);
  bf16* hb = qx;               // h (CAP x 4096 bf16) reuses qx after wo_z
  float* parts = (float*)tx;   // 2 x CAP x 1024 fp32 == CAP x 4096 bf16 bytes

  dim3 tblk(32, 8);
  transpose_cast<<<dim3(3072 / 32, 1024 / 32), tblk, 0, stream>>>(Wqkv, WqkvT, 1024, 3072);
  transpose_cast<<<dim3(1024 / 32, 1024 / 32), tblk, 0, stream>>>(Wg, WgTopT, 1024, 1024);
  transpose_cast<<<dim3(1024 / 32, 1024 / 32), tblk, 0, stream>>>(Wg + 1024 * 1024, WgBotT, 1024, 1024);
  transpose_cast<<<dim3(1024 / 32, 1024 / 32), tblk, 0, stream>>>(Wo, WoT, 1024, 1024);
  transpose_cast<<<dim3(4096 / 32, 1024 / 32), tblk, 0, stream>>>(Wf1, Wf1T, 1024, 4096);
  transpose_cast<<<dim3(1024 / 32, 4096 / 32), tblk, 0, stream>>>(Wf2, Wf2T, 4096, 1024);
  fill_bias<<<16, 256, 0, stream>>>(bqkv, bg, biasA, biasB);

  zero_cnt<<<1, 64, 0, stream>>>(cntp);
  index_build<<<NB / 256, 256, 0, stream>>>(route, cntp, idx, pos);
  gather_cast<<<CAP, 256, 0, stream>>>(img, txt, cntp, idx, xg, tg);

  // qkv+gate for img AND txt in one launch (2 x 26m x 16n blocks)
  gemm256<0><<<2 * MT2 * 16, 512, 0, stream>>>(xg, tg, WqkvT, WgTopT, WgBotT,
                                               biasA, biasB, qx, tx, nullptr, cntp);
  // attention -> cmean
  attn_kernel<<<CAP * 4, 256, 0, stream>>>(qx, tx, cmean, cntp);
  // z = sigmoid(gate)-mix + cmean@Wo + bo
  wo_z_kernel<<<8 * MT, 256, 0, stream>>>(img, txt, qx, tx, WoT, bg, bo, cmean, zb,
                                          cntp, idx);
  // layernorm in-place
  ln_kernel<<<CAP, 256, 0, stream>>>(zb, gamma, beta, cntp);
  // h = gelu(z@Wf1 + bf1)  (overwrites qx)
  gemm256<1><<<MT2 * 16, 512, 0, stream>>>(zb, nullptr, Wf1T, nullptr, nullptr,
                                           bf1, nullptr, hb, nullptr, nullptr, cntp);
  // ffn2 split-K=2 partials (overwrites tx)
  gemm256<2><<<MT2 * 4 * 2, 512, 0, stream>>>(hb, nullptr, Wf2T, nullptr, nullptr,
                                              nullptr, nullptr, nullptr, nullptr,
                                              parts, cntp);
  // out: rc 0/1 copy, rc 2 partial-reduce + bias
  route_out<<<NB, 256, 0, stream>>>(img, txt, route, pos, parts, bf2, (float*)d_out);
}

// Round 7
// 616.721 us; speedup vs baseline: 1.0362x; 1.0362x over previous
//
// Round 11 == Round 10 resubmitted (container acquisition failed twice; no
// kernel result). BK=64 staging (128B rows). R5-R9 proved time invariant to
// every in-loop knob (conflicts, B-reads, vmcnt depth, barrier count) -> the
// limiter is the staging path: 64B-granular gl_lds rows cap aggregate load
// traffic at ~6TB/s (m201's BK=64 sustains ~11.6TB/s; our FETCH=2.8x
// compulsory from 64B sectors in 128B lines). BK=64, 2-slot dbuf (128KB LDS),
// stage kt+1 at start of kt (full-tile slack >= HBM latency), per-wave
// vmcnt(0)+barrier at end of kt (airtight, no tail case). Swizzle: LDS chunk
// position of global chunk c in row r is c^(r&7); writer linear dest +
// inverse-swizzled global source; verified 2-way max (free).
#include <hip/hip_runtime.h>
#include <hip/hip_bf16.h>
#include <math.h>

#define NB 16384      // B
#define DIM 1024      // D
#define CAP 6656      // compacted capacity (count ~5461)
#define MT 52         // CAP/128 m-tiles (wo_z)
#define MT2 26        // CAP/256 m-tiles (gemm256)

using bf16 = __hip_bfloat16;
typedef __attribute__((ext_vector_type(8))) short short8;
typedef __attribute__((ext_vector_type(4))) short short4v;
typedef __attribute__((ext_vector_type(4))) float float4v;

__device__ __forceinline__ void gl_lds16(const void* g, void* l) {
  __builtin_amdgcn_global_load_lds(
      (const __attribute__((address_space(1))) unsigned int*)g,
      (__attribute__((address_space(3))) unsigned int*)l, 16, 0, 0);
}

__device__ __forceinline__ short f2bf(float x) {
  __hip_bfloat16 h = __float2bfloat16(x);
  return *reinterpret_cast<short*>(&h);
}

// bid -> (m0, n0) in 128-tiles: xcd = bid&7 owns n-panels n%8==xcd. nN%8==0.
__device__ __forceinline__ void swz(int bid, int nN, int& m0, int& n0) {
  int x = bid & 7;
  int r = bid >> 3;
  int nl = nN >> 3;
  int nLoc = r % nl;
  int m = r / nl;
  n0 = (x + 8 * nLoc) * 128;
  m0 = m * 128;
}

// 256-tile variant
__device__ __forceinline__ void swz256(int bid, int nN, int& m0, int& n0) {
  int x = bid & 7;
  int r = bid >> 3;
  int nl = nN >> 3;
  n0 = (x + 8 * (r % nl)) * 256;
  m0 = (r / nl) * 256;
}

// ---- stage one 256x64 bf16 tile (32KB) into LDS, BK=64 --------------------
// LDS layout: element (row, col) at element offset row*64 + chunk'*8 + (col&7)
// where chunk = col>>3 (8 x 16B chunks per 128B row), chunk' = chunk ^ (row&7).
// Writer is linear (gl_lds: wave-uniform dest + lane*16B); the swizzle is
// realized by permuting the per-lane GLOBAL source chunk (same involution).
// Each wave-op covers 8 rows x 128B contiguous -> 128B-granular HBM requests.
__device__ __forceinline__ void stage64(const bf16* __restrict__ gbase,
                                        int ld, int kc, bf16* ubase, int t) {
  const int rl = t >> 3;                      // row within 64-row sweep
  const int cs = ((t & 7) ^ (rl & 7)) * 8;    // swizzled source chunk (elems)
  const bf16* src0 = gbase + (size_t)rl * ld + kc + cs;
  bf16* dst0 = ubase + ((t >> 6) << 9);       // wave-uniform base
#pragma unroll
  for (int j = 0; j < 4; ++j)
    gl_lds16(src0 + (size_t)(j * 64) * ld, (void*)(dst0 + j * 4096));
}

// ---------------- 256x256-tile BK=64 double-buffered GEMM ----------------
// MODE 0: qkv+gate, merged img/txt halves. A(CAP,1024)@[Wqkv|WgHalf]^T N=4096.
// MODE 1: ffn1 gelu. A=zb(CAP,1024) @ Wf1T, N=4096.
// MODE 2: ffn2 split-K=2 fp32 partials. A=hb(CAP,4096) @ Wf2T, N=1024.
template <int MODE>
__global__ __launch_bounds__(512, 2) void gemm256(
    const bf16* __restrict__ A0, const bf16* __restrict__ A1,
    const bf16* __restrict__ B0, const bf16* __restrict__ Bg0,
    const bf16* __restrict__ Bg1, const float* __restrict__ bias0,
    const float* __restrict__ bias1, bf16* __restrict__ O0,
    bf16* __restrict__ O1, float* __restrict__ P,
    const int* __restrict__ cntp) {
  const int cnt = *cntp;
  int bid = blockIdx.x;
  int g = 0, sk = 0, m0, n0;
  if constexpr (MODE == 0) {
    g = bid >= 416;
    bid -= g * 416;
    swz256(bid, 16, m0, n0);
  } else if constexpr (MODE == 1) {
    swz256(bid, 16, m0, n0);
  } else {
    sk = bid / 104;
    int rm = bid % 104;
    m0 = (rm >> 2) * 256;
    n0 = (rm & 3) * 256;
  }
  if (m0 >= ((cnt + 255) & ~255)) return;

  constexpr int LDA = (MODE == 2) ? 4096 : 1024;
  constexpr int LDB = (MODE == 2) ? 4096 : 1024;
  constexpr int NK = (MODE == 2) ? 32 : 16;   // BK=64 K-tiles
  const int kb = (MODE == 2) ? sk * 2048 : 0;

  const bf16* Ab;
  const bf16* Bt;
  if constexpr (MODE == 0) {
    Ab = (g ? A1 : A0) + (size_t)m0 * LDA;
    Bt = (n0 < 3072) ? B0 + (size_t)n0 * 1024
                     : (g ? Bg1 : Bg0) + (size_t)(n0 - 3072) * 1024;
  } else {
    Ab = A0 + (size_t)m0 * LDA;
    Bt = B0 + (size_t)n0 * LDB;
  }

  alignas(16) __shared__ bf16 lds[2][2][16384];  // 2 slots x {A,B} x 32KB
  const int t = threadIdx.x;
  const int wave = t >> 6, lane = t & 63;
  const int wm = wave >> 2, wn = wave & 3;   // 2M x 4N waves, 128x64 out/wave
  const int r16 = lane & 15, quad = lane >> 4;
  const int r7 = r16 & 7;
  const int ck0 = (quad ^ r7) * 8;           // kk=0 swizzled chunk (elements)
  const int ck1 = ((4 + quad) ^ r7) * 8;     // kk=1

  // prologue: stage tile 0 into slot 0
  stage64(Ab, LDA, kb, &lds[0][0][0], t);
  stage64(Bt, LDB, kb, &lds[0][1][0], t);
  asm volatile("s_waitcnt vmcnt(0)" ::: "memory");
  __builtin_amdgcn_s_barrier();

  float4v acc[8][4] = {};
#pragma unroll 2
  for (int kt = 0; kt < NK; ++kt) {
    const int sl = kt & 1;
    // stage kt+1 into the slot read during kt-1 (its readers completed before
    // the kt-1 end barrier via lgkmcnt(0)).
    if (kt + 1 < NK) {
      stage64(Ab, LDA, kb + (kt + 1) * 64, &lds[sl ^ 1][0][0], t);
      stage64(Bt, LDB, kb + (kt + 1) * 64, &lds[sl ^ 1][1][0], t);
    }
    const bf16* aU = &lds[sl][0][0];
    const bf16* bU = &lds[sl][1][0];
    short8 av[8], bv[4];
    // ---- kk = 0 half ----
#pragma unroll
    for (int mi = 0; mi < 8; ++mi)
      av[mi] = *(const short8*)(aU + (wm * 128 + mi * 16 + r16) * 64 + ck0);
#pragma unroll
    for (int ni = 0; ni < 4; ++ni)
      bv[ni] = *(const short8*)(bU + (wn * 64 + ni * 16 + r16) * 64 + ck0);
    asm volatile("s_waitcnt lgkmcnt(0)" ::: "memory");
    __builtin_amdgcn_s_setprio(1);
#pragma unroll
    for (int mi = 0; mi < 8; ++mi)
#pragma unroll
      for (int ni = 0; ni < 4; ++ni)
        acc[mi][ni] = __builtin_amdgcn_mfma_f32_16x16x32_bf16(
            av[mi], bv[ni], acc[mi][ni], 0, 0, 0);
    __builtin_amdgcn_s_setprio(0);
    // ---- kk = 1 half ----
#pragma unroll
    for (int mi = 0; mi < 8; ++mi)
      av[mi] = *(const short8*)(aU + (wm * 128 + mi * 16 + r16) * 64 + ck1);
#pragma unroll
    for (int ni = 0; ni < 4; ++ni)
      bv[ni] = *(const short8*)(bU + (wn * 64 + ni * 16 + r16) * 64 + ck1);
    asm volatile("s_waitcnt lgkmcnt(0)" ::: "memory");
    __builtin_amdgcn_s_setprio(1);
#pragma unroll
    for (int mi = 0; mi < 8; ++mi)
#pragma unroll
      for (int ni = 0; ni < 4; ++ni)
        acc[mi][ni] = __builtin_amdgcn_mfma_f32_16x16x32_bf16(
            av[mi], bv[ni], acc[mi][ni], 0, 0, 0);
    __builtin_amdgcn_s_setprio(0);
    // tile kt+1 landed: each wave drains its own 8 staging loads, then the
    // barrier guarantees all waves' loads are in LDS.
    if (kt + 1 < NK) asm volatile("s_waitcnt vmcnt(0)" ::: "memory");
    __builtin_amdgcn_s_barrier();
  }

  const int colb = n0 + wn * 64 + r16;
  if constexpr (MODE == 2) {
    float* out = P + (size_t)sk * CAP * 1024;
#pragma unroll
    for (int nf = 0; nf < 4; ++nf) {
      int gcol = colb + nf * 16;
#pragma unroll
      for (int mf = 0; mf < 8; ++mf)
#pragma unroll
        for (int r = 0; r < 4; ++r) {
          int grow = m0 + wm * 128 + mf * 16 + quad * 4 + r;
          out[(size_t)grow * 1024 + gcol] = acc[mf][nf][r];
        }
    }
  } else {
    const float* bias = (MODE == 0) ? (g ? bias1 : bias0) : bias0;
    bf16* O = (MODE == 0) ? (g ? O1 : O0) : O0;
    float bvv[4];
#pragma unroll
    for (int nf = 0; nf < 4; ++nf) bvv[nf] = bias[colb + nf * 16];
#pragma unroll
    for (int nf = 0; nf < 4; ++nf) {
      int gcol = colb + nf * 16;
#pragma unroll
      for (int mf = 0; mf < 8; ++mf)
#pragma unroll
        for (int r = 0; r < 4; ++r) {
          int grow = m0 + wm * 128 + mf * 16 + quad * 4 + r;
          float v = acc[mf][nf][r] + bvv[nf];
          if constexpr (MODE == 1)
            v = 0.5f * v * (1.f + erff(v * 0.70710678118654752f));
          O[(size_t)grow * 4096 + gcol] = __float2bfloat16(v);
        }
    }
  }
}

// ---------------- transpose + cast weight (K,N) fp32 -> (N,K) bf16 ----------
__global__ __launch_bounds__(256) void transpose_cast(
    const float* __restrict__ in, bf16* __restrict__ out, int K, int N) {
  __shared__ float tile[32][33];
  int n0 = blockIdx.x * 32, k0 = blockIdx.y * 32;
  int tx = threadIdx.x, ty = threadIdx.y;  // 32 x 8
#pragma unroll
  for (int i = 0; i < 32; i += 8)
    tile[ty + i][tx] = in[(size_t)(k0 + ty + i) * N + n0 + tx];
  __syncthreads();
#pragma unroll
  for (int i = 0; i < 32; i += 8)
    out[(size_t)(n0 + ty + i) * K + k0 + tx] = __float2bfloat16(tile[tx][ty + i]);
}

// ---------------- bias concat buffers for qkvg GEMMs ----------------
__global__ __launch_bounds__(256) void fill_bias(const float* __restrict__ bqkv,
                                                 const float* __restrict__ bg,
                                                 float* __restrict__ biasA,
                                                 float* __restrict__ biasB) {
  int i = blockIdx.x * 256 + threadIdx.x;  // < 4096
  float qv = (i < 3072) ? bqkv[i] : 0.f;
  biasA[i] = qv;
  biasB[i] = (i < 3072) ? qv : bg[i - 3072];
}

// ---------------- compaction ----------------
__global__ void zero_cnt(int* cnt) { if (threadIdx.x == 0) *cnt = 0; }

__global__ __launch_bounds__(256) void index_build(const int* __restrict__ route,
                                                   int* __restrict__ cnt,
                                                   int* __restrict__ idx,
                                                   int* __restrict__ pos) {
  int r = blockIdx.x * 256 + threadIdx.x;
  if (r < NB && route[r] == 2) {
    int p = atomicAdd(cnt, 1);
    idx[p] = r;
    pos[r] = p;
  }
}

__global__ __launch_bounds__(256) void gather_cast(
    const float* __restrict__ img, const float* __restrict__ txt,
    const int* __restrict__ cnt, const int* __restrict__ idx,
    bf16* __restrict__ xg, bf16* __restrict__ tg) {
  int n = blockIdx.x;
  if (n >= *cnt) return;
  int r = idx[n];
  int c = threadIdx.x * 4;
  float4 vi = *(const float4*)(img + (size_t)r * DIM + c);
  float4 vt = *(const float4*)(txt + (size_t)r * DIM + c);
  short4v pi, pt;
  pi[0] = f2bf(vi.x); pi[1] = f2bf(vi.y); pi[2] = f2bf(vi.z); pi[3] = f2bf(vi.w);
  pt[0] = f2bf(vt.x); pt[1] = f2bf(vt.y); pt[2] = f2bf(vt.z); pt[3] = f2bf(vt.w);
  *(short4v*)(xg + (size_t)n * DIM + c) = pi;
  *(short4v*)(tg + (size_t)n * DIM + c) = pt;
}

// ---------------- seq-len-2 attention ----------------
__global__ __launch_bounds__(256) void attn_kernel(const bf16* __restrict__ qx,
                                                   const bf16* __restrict__ tx,
                                                   bf16* __restrict__ cmean,
                                                   const int* __restrict__ cntp) {
  const int cnt = *cntp;
  int gw = blockIdx.x * 4 + (threadIdx.x >> 6);
  int lane = threadIdx.x & 63;
  int n = gw >> 4, h = gw & 15;
  if (n >= ((cnt + 127) & ~127)) return;
  const bf16* b0 = qx + (size_t)n * 4096 + h * 64 + lane;
  const bf16* b1 = tx + (size_t)n * 4096 + h * 64 + lane;
  float q0 = __bfloat162float(b0[0]);
  float k0 = __bfloat162float(b0[1024]);
  float v0 = __bfloat162float(b0[2048]);
  float q1 = __bfloat162float(b1[0]);
  float k1 = __bfloat162float(b1[1024]);
  float v1 = __bfloat162float(b1[2048]);
  float s00 = q0 * k0, s01 = q0 * k1, s10 = q1 * k0, s11 = q1 * k1;
#pragma unroll
  for (int d = 32; d > 0; d >>= 1) {
    s00 += __shfl_xor(s00, d);
    s01 += __shfl_xor(s01, d);
    s10 += __shfl_xor(s10, d);
    s11 += __shfl_xor(s11, d);
  }
  const float sc = 0.125f;
  s00 *= sc; s01 *= sc; s10 *= sc; s11 *= sc;
  float m0 = fmaxf(s00, s01), m1 = fmaxf(s10, s11);
  float e00 = expf(s00 - m0), e01 = expf(s01 - m0);
  float e10 = expf(s10 - m1), e11 = expf(s11 - m1);
  float i0 = 1.f / (e00 + e01), i1 = 1.f / (e10 + e11);
  float c0 = (e00 * i0) * v0 + (e01 * i0) * v1;
  float c1 = (e10 * i1) * v0 + (e11 * i1) * v1;
  cmean[(size_t)n * DIM + h * 64 + lane] = __float2bfloat16(0.5f * (c0 + c1));
}

// ---------------- wo_z: z = fmix + cmean@Wo + bo (128^2 structure) ---------
__global__ __launch_bounds__(256) void wo_z_kernel(
    const float* __restrict__ img, const float* __restrict__ txt,
    const bf16* __restrict__ qx, const bf16* __restrict__ tx,
    const bf16* __restrict__ WoT, const float* __restrict__ bg,
    const float* __restrict__ bo, const bf16* __restrict__ cmean,
    bf16* __restrict__ z, const int* __restrict__ cntp, const int* __restrict__ idx) {
  const int cnt = *cntp;
  int m0, n0;
  swz(blockIdx.x, 8, m0, n0);
  if (m0 >= ((cnt + 127) & ~127)) return;
  alignas(16) __shared__ bf16 sA[128 * 32];
  alignas(16) __shared__ bf16 sB[128 * 32];
  const int t = threadIdx.x;
  const int wave = t >> 6, lane = t & 63;
  const int wm = (wave >> 1) * 64, wn = (wave & 1) * 64;
  const int r16 = lane & 15, quad = lane >> 4;

  float4v acc[4][4] = {};
  for (int k0 = 0; k0 < 1024; k0 += 32) {
    if (k0) __syncthreads();
#pragma unroll
    for (int j = 0; j < 2; ++j) {
      int c = t + j * 256;
      int row = c >> 2;
      int kk = k0 + (c & 3) * 8;
      gl_lds16(WoT + (size_t)(n0 + row) * 1024 + kk, (void*)(sB + j * 2048 + wave * 512));
      gl_lds16(cmean + (size_t)(m0 + row) * 1024 + kk, (void*)(sA + j * 2048 + wave * 512));
    }
    __syncthreads();
    short8 af[4], bfr[4];
#pragma unroll
    for (int i = 0; i < 4; ++i) {
      af[i] = *(const short8*)(sA + (wm + i * 16 + r16) * 32 + quad * 8);
      bfr[i] = *(const short8*)(sB + (wn + i * 16 + r16) * 32 + quad * 8);
    }
#pragma unroll
    for (int i = 0; i < 4; ++i)
#pragma unroll
      for (int j = 0; j < 4; ++j)
        acc[i][j] =
            __builtin_amdgcn_mfma_f32_16x16x32_bf16(af[i], bfr[j], acc[i][j], 0, 0, 0);
  }
#pragma unroll
  for (int i = 0; i < 4; ++i)
#pragma unroll
    for (int j = 0; j < 4; ++j) {
      int gcol = n0 + wn + j * 16 + r16;
      float bgv = bg[gcol], bov = bo[gcol];
#pragma unroll
      for (int r = 0; r < 4; ++r) {
        int grow = m0 + wm + i * 16 + quad * 4 + r;
        float zv = 0.f;
        if (grow < cnt) {
          int orow = idx[grow];
          float gp = __bfloat162float(qx[(size_t)grow * 4096 + 3072 + gcol]) +
                     __bfloat162float(tx[(size_t)grow * 4096 + 3072 + gcol]) + bgv;
          float g = 1.f / (1.f + expf(-gp));
          size_t ii = (size_t)orow * DIM + gcol;
          float fm = g * img[ii] + (1.f - g) * txt[ii];
          zv = fm + acc[i][j][r] + bov;
        }
        z[(size_t)grow * DIM + gcol] = __float2bfloat16(zv);
      }
    }
}

// ---------------- layernorm in-place ----------------
__global__ __launch_bounds__(256) void ln_kernel(bf16* __restrict__ z,
                                                 const float* __restrict__ g,
                                                 const float* __restrict__ be,
                                                 const int* __restrict__ cntp) {
  const int cnt = *cntp;
  int b = blockIdx.x, t = threadIdx.x;
  if (b >= ((cnt + 127) & ~127)) return;
  bf16* zr = z + (size_t)b * DIM;
  float v[4];
  float s = 0.f, s2 = 0.f;
#pragma unroll
  for (int i = 0; i < 4; ++i) {
    float x = __bfloat162float(zr[t + 256 * i]);
    v[i] = x; s += x; s2 += x * x;
  }
#pragma unroll
  for (int d = 32; d > 0; d >>= 1) {
    s += __shfl_xor(s, d);
    s2 += __shfl_xor(s2, d);
  }
  __shared__ float rs[4], rs2[4];
  int w = t >> 6, lane = t & 63;
  if (!lane) { rs[w] = s; rs2[w] = s2; }
  __syncthreads();
  s = rs[0] + rs[1] + rs[2] + rs[3];
  s2 = rs2[0] + rs2[1] + rs2[2] + rs2[3];
  float mu = s * (1.f / 1024.f);
  float var = s2 * (1.f / 1024.f) - mu * mu;
  float r = rsqrtf(var + 1e-5f);
#pragma unroll
  for (int i = 0; i < 4; ++i) {
    int c = t + 256 * i;
    zr[c] = __float2bfloat16((v[i] - mu) * r * g[c] + be[c]);
  }
}

// ---------------- unified output: copy rc 0/1, reduce partials rc 2 --------
__global__ __launch_bounds__(256) void route_out(
    const float* __restrict__ img, const float* __restrict__ txt,
    const int* __restrict__ route, const int* __restrict__ pos,
    const float* __restrict__ parts, const float* __restrict__ bf2,
    float* __restrict__ out) {
  int row = blockIdx.x;
  int rc = route[row];
  int c = threadIdx.x * 4;
  float4 v;
  if (rc == 2) {
    int n = pos[row];
    float4 p0 = *(const float4*)(parts + (size_t)n * 1024 + c);
    float4 p1 = *(const float4*)(parts + (size_t)CAP * 1024 + (size_t)n * 1024 + c);
    float4 b = *(const float4*)(bf2 + c);
    v.x = p0.x + p1.x + b.x;
    v.y = p0.y + p1.y + b.y;
    v.z = p0.z + p1.z + b.z;
    v.w = p0.w + p1.w + b.w;
  } else {
    const float* src = (rc == 0) ? img : txt;
    v = *(const float4*)(src + (size_t)row * DIM + c);
  }
  *(float4*)(out + (size_t)row * DIM + c) = v;
}

extern "C" void kernel_launch(void* const* d_in, const int* in_sizes, int n_in,
                              void* d_out, int out_size, void* d_ws, size_t ws_size,
                              hipStream_t stream) {
  const float* img = (const float*)d_in[0];
  const float* txt = (const float*)d_in[1];
  const int* route = (const int*)d_in[2];
  const float* Wg = (const float*)d_in[3];
  const float* bg = (const float*)d_in[4];
  const float* Wqkv = (const float*)d_in[5];
  const float* bqkv = (const float*)d_in[6];
  const float* Wo = (const float*)d_in[7];
  const float* bo = (const float*)d_in[8];
  const float* gamma = (const float*)d_in[9];
  const float* beta = (const float*)d_in[10];
  const float* Wf1 = (const float*)d_in[11];
  const float* bf1 = (const float*)d_in[12];
  const float* Wf2 = (const float*)d_in[13];
  const float* bf2 = (const float*)d_in[14];

  char* ws = (char*)d_ws;
  size_t off = 0;
  auto alloc = [&](size_t bytes) {
    char* p = ws + off;
    off += (bytes + 255) & ~(size_t)255;
    return p;
  };
  int* cntp = (int*)alloc(256);
  int* idx = (int*)alloc((size_t)NB * 4);
  int* pos = (int*)alloc((size_t)NB * 4);
  float* biasA = (float*)alloc(4096 * 4);
  float* biasB = (float*)alloc(4096 * 4);
  bf16* WqkvT = (bf16*)alloc((size_t)3072 * 1024 * 2);
  bf16* WgTopT = (bf16*)alloc((size_t)1024 * 1024 * 2);
  bf16* WgBotT = (bf16*)alloc((size_t)1024 * 1024 * 2);
  bf16* WoT = (bf16*)alloc((size_t)1024 * 1024 * 2);
  bf16* Wf1T = (bf16*)alloc((size_t)4096 * 1024 * 2);
  bf16* Wf2T = (bf16*)alloc((size_t)1024 * 4096 * 2);
  bf16* xg = (bf16*)alloc((size_t)CAP * 1024 * 2);
  bf16* tg = (bf16*)alloc((size_t)CAP * 1024 * 2);
  bf16* qx = (bf16*)alloc((size_t)CAP * 4096 * 2);  // qkv+gate (img); later h
  bf16* tx = (bf16*)alloc((size_t)CAP * 4096 * 2);  // qkv+gate (txt); later partials
  bf16* cmean = (bf16*)alloc((size_t)CAP * 1024 * 2);
  bf16* zb = (bf16*)alloc((size_t)CAP * 1024 * 2);
  bf16* hb = qx;               // h (CAP x 4096 bf16) reuses qx after wo_z
  float* parts = (float*)tx;   // 2 x CAP x 1024 fp32 == CAP x 4096 bf16 bytes

  dim3 tblk(32, 8);
  transpose_cast<<<dim3(3072 / 32, 1024 / 32), tblk, 0, stream>>>(Wqkv, WqkvT, 1024, 3072);
  transpose_cast<<<dim3(1024 / 32, 1024 / 32), tblk, 0, stream>>>(Wg, WgTopT, 1024, 1024);
  transpose_cast<<<dim3(1024 / 32, 1024 / 32), tblk, 0, stream>>>(Wg + 1024 * 1024, WgBotT, 1024, 1024);
  transpose_cast<<<dim3(1024 / 32, 1024 / 32), tblk, 0, stream>>>(Wo, WoT, 1024, 1024);
  transpose_cast<<<dim3(4096 / 32, 1024 / 32), tblk, 0, stream>>>(Wf1, Wf1T, 1024, 4096);
  transpose_cast<<<dim3(1024 / 32, 4096 / 32), tblk, 0, stream>>>(Wf2, Wf2T, 4096, 1024);
  fill_bias<<<16, 256, 0, stream>>>(bqkv, bg, biasA, biasB);

  zero_cnt<<<1, 64, 0, stream>>>(cntp);
  index_build<<<NB / 256, 256, 0, stream>>>(route, cntp, idx, pos);
  gather_cast<<<CAP, 256, 0, stream>>>(img, txt, cntp, idx, xg, tg);

  // qkv+gate for img AND txt in one launch (2 x 26m x 16n blocks)
  gemm256<0><<<2 * MT2 * 16, 512, 0, stream>>>(xg, tg, WqkvT, WgTopT, WgBotT,
                                               biasA, biasB, qx, tx, nullptr, cntp);
  // attention -> cmean
  attn_kernel<<<CAP * 4, 256, 0, stream>>>(qx, tx, cmean, cntp);
  // z = sigmoid(gate)-mix + cmean@Wo + bo
  wo_z_kernel<<<8 * MT, 256, 0, stream>>>(img, txt, qx, tx, WoT, bg, bo, cmean, zb,
                                          cntp, idx);
  // layernorm in-place
  ln_kernel<<<CAP, 256, 0, stream>>>(zb, gamma, beta, cntp);
  // h = gelu(z@Wf1 + bf1)  (overwrites qx)
  gemm256<1><<<MT2 * 16, 512, 0, stream>>>(zb, nullptr, Wf1T, nullptr, nullptr,
                                           bf1, nullptr, hb, nullptr, nullptr, cntp);
  // ffn2 split-K=2 partials (overwrites tx)
  gemm256<2><<<MT2 * 4 * 2, 512, 0, stream>>>(hb, nullptr, Wf2T, nullptr, nullptr,
                                              nullptr, nullptr, nullptr, nullptr,
                                              parts, cntp);
  // out: rc 0/1 copy, rc 2 partial-reduce + bias
  route_out<<<NB, 256, 0, stream>>>(img, txt, route, pos, parts, bf2, (float*)d_out);
}